// Round 5
// baseline (271.963 us; speedup 1.0000x reference)
//
#include <hip/hip_runtime.h>
#include <math.h>

#define L 2048
#define BATCH 8
#define RPS 16               // rows per block in stats kernel (4 waves x 4 rows)
#define NSPLIT (L / RPS)     // 128 column-partial slabs per batch
#define EPSF 1e-8f
#define C2 2.885390081777927f   // 2/ln2 : exp(2x) = exp2(x*C2)
#define C4 5.770780163555854f   // 4/ln2 : exp(4x) = exp2(x*C4)

__device__ __forceinline__ float fexp2(float x) {
  return __builtin_amdgcn_exp2f(x);   // v_exp_f32
}

// Block = 256 threads (4 waves). Wave w owns rows i0+4w .. i0+4w+3 (whole rows).
// Column-steps beyond ceil(len1/256) are never loaded (masked region contributes 0).
// Row sums: per-lane register accumulator + one 6-shuffle butterfly per row.
// Column sums: up to 32 per-lane registers, merged across the 4 waves via LDS.
__global__ __launch_bounds__(256) void stats_k(
    const float* __restrict__ sim, const int* __restrict__ lengths,
    float* __restrict__ rinv, float* __restrict__ pcol) {
  const int b = blockIdx.y;
  const int islab = blockIdx.x;
  const int len0 = lengths[2 * b], len1 = lengths[2 * b + 1];
  const int smax = (len1 + 255) >> 8;        // 4..8 valid 256-col steps (len1>=1024)
  const int tid = threadIdx.x;
  const int wave = tid >> 6, lane = tid & 63;
  const int i0 = islab * RPS + wave * 4;
  const int jb = lane * 4;

  float4 cacc[8];
#pragma unroll
  for (int s = 0; s < 8; ++s) cacc[s] = make_float4(0.f, 0.f, 0.f, 0.f);

  for (int r = 0; r < 4; ++r) {
    const int i = i0 + r;
    if (i >= len0) break;                    // wave-uniform; rows >= len0 contribute 0
    const float* p = sim + ((size_t)b * L + i) * L + jb;
    float racc = 0.f;
#pragma unroll
    for (int s = 0; s < 4; ++s) {            // len1 >= 1024: always fully valid
      float4 v = *reinterpret_cast<const float4*>(p + s * 256);
      float4 e;
      e.x = fexp2(v.x * C2); e.y = fexp2(v.y * C2);
      e.z = fexp2(v.z * C2); e.w = fexp2(v.w * C2);
      racc += (e.x + e.y) + (e.z + e.w);
      cacc[s].x += e.x; cacc[s].y += e.y; cacc[s].z += e.z; cacc[s].w += e.w;
    }
    for (int s = 4; s < smax; ++s) {         // boundary steps, per-component mask
      float4 v = *reinterpret_cast<const float4*>(p + s * 256);
      const int j = s * 256 + jb;
      float4 e;
      e.x = (j + 0 < len1) ? fexp2(v.x * C2) : 0.f;
      e.y = (j + 1 < len1) ? fexp2(v.y * C2) : 0.f;
      e.z = (j + 2 < len1) ? fexp2(v.z * C2) : 0.f;
      e.w = (j + 3 < len1) ? fexp2(v.w * C2) : 0.f;
      racc += (e.x + e.y) + (e.z + e.w);
      cacc[s].x += e.x; cacc[s].y += e.y; cacc[s].z += e.z; cacc[s].w += e.w;
    }
#pragma unroll
    for (int off = 1; off < 64; off <<= 1) racc += __shfl_xor(racc, off, 64);
    if (lane == 0) rinv[(size_t)b * L + i] = 1.0f / racc;
  }

  __shared__ float cpart[4][2048];           // 32 KB
  for (int s = 0; s < smax; ++s)
    *reinterpret_cast<float4*>(&cpart[wave][s * 256 + jb]) = cacc[s];
  __syncthreads();

  const int cmax = smax << 8;
#pragma unroll
  for (int h = 0; h < 2; ++h) {
    const int c = h * 1024 + tid * 4;
    if (c < cmax) {
      float4 a0 = *reinterpret_cast<const float4*>(&cpart[0][c]);
      float4 a1 = *reinterpret_cast<const float4*>(&cpart[1][c]);
      float4 a2 = *reinterpret_cast<const float4*>(&cpart[2][c]);
      float4 a3 = *reinterpret_cast<const float4*>(&cpart[3][c]);
      float4 o;
      o.x = (a0.x + a1.x) + (a2.x + a3.x);
      o.y = (a0.y + a1.y) + (a2.y + a3.y);
      o.z = (a0.z + a1.z) + (a2.z + a3.z);
      o.w = (a0.w + a1.w) + (a2.w + a3.w);
      *reinterpret_cast<float4*>(&pcol[(size_t)(b * NSPLIT + islab) * L + c]) = o;
    }
  }
}

__global__ __launch_bounds__(256) void col_merge_k(
    const float* __restrict__ pcol, const int* __restrict__ lengths,
    float* __restrict__ cinv) {
  const int idx = blockIdx.x * 256 + threadIdx.x;  // b*L + j
  const int b = idx >> 11, j = idx & (L - 1);
  if (j >= lengths[2 * b + 1]) return;             // pcol never written there (poison)
  const float* p = pcol + (size_t)b * NSPLIT * L + j;
  float s = 0.f;
#pragma unroll 16
  for (int c = 0; c < NSPLIT; ++c) s += p[(size_t)c * L];
  cinv[idx] = 1.0f / s;
}

__global__ __launch_bounds__(512) void finalize_k(
    const float* __restrict__ sim, const int* __restrict__ lengths,
    const float* __restrict__ rinv, const float* __restrict__ cinv,
    float* __restrict__ out) {
  const int row = blockIdx.x;          // b*L + i ; one block = one full row
  const int b = row >> 11, i = row & (L - 1);
  const int len0 = lengths[2 * b], len1 = lengths[2 * b + 1];
  const int j = threadIdx.x * 4;
  const size_t off = (size_t)row * L + j;
  float4 o = make_float4(0.f, 0.f, 0.f, 0.f);
  if (i < len0 && j < len1) {          // skip loads entirely in the masked region
    const float ri = rinv[row];
    float4 v = *reinterpret_cast<const float4*>(sim + off);
    float4 ci = *reinterpret_cast<const float4*>(cinv + ((size_t)b << 11) + j);
    o.x = sqrtf(EPSF + fexp2(v.x * C4) * ri * ci.x);
    o.y = (j + 1 < len1) ? sqrtf(EPSF + fexp2(v.y * C4) * ri * ci.y) : 0.f;
    o.z = (j + 2 < len1) ? sqrtf(EPSF + fexp2(v.z * C4) * ri * ci.z) : 0.f;
    o.w = (j + 3 < len1) ? sqrtf(EPSF + fexp2(v.w * C4) * ri * ci.w) : 0.f;
  }
  *reinterpret_cast<float4*>(out + off) = o;
}

extern "C" void kernel_launch(void* const* d_in, const int* in_sizes, int n_in,
                              void* d_out, int out_size, void* d_ws, size_t ws_size,
                              hipStream_t stream) {
  const float* sim = (const float*)d_in[0];
  const int* lengths = (const int*)d_in[1];
  float* out = (float*)d_out;
  float* ws = (float*)d_ws;

  const int NR = BATCH * L;  // 16384
  float* rinv = ws;
  float* cinv = ws + NR;
  float* pcol = ws + 2 * (size_t)NR;
  // ws use: 2*16384 + 8*128*2048 floats = ~8.1 MiB

  hipLaunchKernelGGL(stats_k, dim3(NSPLIT, BATCH), dim3(256), 0, stream,
                     sim, lengths, rinv, pcol);
  hipLaunchKernelGGL(col_merge_k, dim3(NR / 256), dim3(256), 0, stream,
                     pcol, lengths, cinv);
  hipLaunchKernelGGL(finalize_k, dim3(NR), dim3(512), 0, stream,
                     sim, lengths, rinv, cinv, out);
}